// Round 7
// baseline (194.989 us; speedup 1.0000x reference)
//
#include <hip/hip_runtime.h>
#include <hip/hip_bf16.h>

// CapsuleLayer dynamic routing. B=64, I=2048, D=16, J=32, K=16, routings=3.
// Structure: uhat never hits HBM; pass p recomputes u_hat (MFMA) and uses
// b_t = u_hat . vsum linearity. 3 passes + 3 squash reductions.
// History: r15-r17 passes stuck ~38-40us; 3 pipelining attempts NULL =>
// latency was not the limiter. Work audit: 16x16x32 mapping wasted half of
// K (d=16 zero-padded), 128 MFMA/i/block, ~35 LDS-pipe ops/wave/i (8 waves
// share one LDS pipe), plus a full second MFMA sweep. squashN was ~24us
// (128-KB-stride walk), not 8.
// Round 18: re-map to mfma_f32_32x32x16_bf16 (K=d=16 EXACT):
//  - A = W^T-pair (rows=(jp,k), 16 d), B = x (cols=32 b): one MFMA = 32b x 2j
//    => 32 MFMA/i/block (4x fewer), 4 A-ds_reads/wave/i (vs 32 total before).
//  - C layout (m74/m101-verified): col=lane&31=b, row=(reg&3)+8*(reg>>2)+4h
//    => k-reduce is 8 in-lane FMA + ONE shfl_xor(32); PV is in-lane FMA on
//    the live u-registers: sweep 2 DELETED.
//  - No zero padding => zbuf gone, all lanes productive.
//  - Final store via ctile transpose (r13: never scatter stores), part
//    layout [b][p][jk] so squashN walks 2-KB stride in a 512-KB slab.
//  - W staged [j][k][d] bf16 rows at 48-B stride (proven bank profile),
//    single buffer + register prefetch (nv), raw lgkmcnt-only barriers (r17).
// Lessons kept: never force min-waves (r8); ctile for scattered stores (r13);
// hipcc drains vmcnt at __syncthreads (r16) -> bar_lds everywhere in pass.

#define B_ 64
#define I_ 2048
#define D_ 16
#define J_ 32
#define K_ 16
#define JK 512    // J_*K_
#define NBLK 256  // pass grid; part = 64*NBLK*512*4 = 32MB
#define GI 8      // i's per block

typedef __attribute__((ext_vector_type(8))) short short8;
typedef __attribute__((ext_vector_type(16))) float float16v;

#define SMEM_BYTES 135168  // max(wlds 24576 + ebuf 2048, ctile 8*32*132*4)

__device__ __forceinline__ unsigned short f2bf(float f) {
    union { float f; unsigned int i; } v;
    v.f = f;
    const unsigned int x = v.i;
    return (unsigned short)((x + 0x7fffu + ((x >> 16) & 1u)) >> 16);  // RNE
}

// LDS-only barrier: leaves global loads in flight (no vmcnt drain).
__device__ __forceinline__ void bar_lds() {
    asm volatile("s_waitcnt lgkmcnt(0)\n\ts_barrier" ::: "memory");
}

// ---------------------------------------------------------------------------
// Fused routing pass. MODE 0: acc += u_hat (uniform c; 1/32 in squash).
// MODE 1: acc += softmax_j(u_hat . vsum) * u_hat.
// Grid NBLK x 512 (8 waves): wave w: bt=w&1 (b-tile of 32), jg=w>>1 (j-octet).
// Lane: b = bt*32 + (lane&31); h = lane>>5 selects d-half (frags) / k-half (C).
// Per i: 4 MFMAs 32x32x16 -> u[4] (64 f32): reg r of MFMA m holds
// u_hat[b][j=jg*8+m*2+(r>>3)][k=(r&3)+8*((r>>2)&1)+4h].
// ---------------------------------------------------------------------------
template <int MODE>
__global__ __launch_bounds__(512)
void caps_pass(const float* __restrict__ x, const float* __restrict__ W,
               const float* __restrict__ vsum, float* __restrict__ part) {
    extern __shared__ char smem[];
    unsigned short* wlds = (unsigned short*)smem;   // 24576 B: [j*16+k]*24 + d
    float* ebuf = (float*)(smem + 24576);           // [par][bt][jg][b32] 2 KB
    float* ct = (float*)smem;                       // end-phase alias (135 KB)

    const int tid = threadIdx.x;
    const int lane = tid & 63;
    const int w = tid >> 6;   // 0..7
    const int bt = w & 1;
    const int jg = w >> 1;    // 0..3
    const int l31 = lane & 31;
    const int h = lane >> 5;
    const int b = bt * 32 + l31;
    const int i0 = blockIdx.x * GI;

    // vv[m][jp][q4]: v[b][j=jg*8+m*2+jp][k in {4h..4h+3}, {8+4h..8+4h+3}]
    float4 vv[4][2][2];
    if (MODE == 1) {
#pragma unroll
        for (int m = 0; m < 4; ++m)
#pragma unroll
            for (int jp = 0; jp < 2; ++jp) {
                const float* vp =
                    vsum + b * JK + (jg * 8 + m * 2 + jp) * 16 + 4 * h;
                vv[m][jp][0] = reinterpret_cast<const float4*>(vp)[0];
                vv[m][jp][1] = reinterpret_cast<const float4*>(vp + 8)[0];
            }
    }

    float16v acc[4];
#pragma unroll
    for (int m = 0; m < 4; ++m)
#pragma unroll
        for (int r = 0; r < 16; ++r) acc[m][r] = 0.f;

    const int sj = tid >> 4;  // staging: j row 0..31
    const int sk = tid & 15;  // staging: k
    const float* wp = W + (size_t)i0 * (J_ * D_ * K_) + sj * (D_ * K_) + sk;

    // ---- prologue: load + stage W[i0] (rows [j][k] of 16 d's, 48-B stride)
    {
        float vals[16];
#pragma unroll
        for (int d = 0; d < 16; ++d) vals[d] = wp[d * K_];
        unsigned int pk[8];
#pragma unroll
        for (int q = 0; q < 8; ++q)
            pk[q] = ((unsigned int)f2bf(vals[2 * q + 1]) << 16) |
                    f2bf(vals[2 * q]);
        uint4* dst = reinterpret_cast<uint4*>(wlds + (sj * 16 + sk) * 24);
        uint4 w0; w0.x = pk[0]; w0.y = pk[1]; w0.z = pk[2]; w0.w = pk[3];
        uint4 w1; w1.x = pk[4]; w1.y = pk[5]; w1.z = pk[6]; w1.w = pk[7];
        dst[0] = w0; dst[1] = w1;
    }

    // A-frag lane address (shorts): row (j, k) = ((jg*8 + jp)*16 + k), d-half h
    const int abase = ((jg * 8 + (l31 >> 4)) * 16 + (lane & 15)) * 24 + h * 8;
    const float* xbase = x + (size_t)b * I_ * D_ + h * 8;

    for (int t = 0; t < GI; ++t) {
        const int i = i0 + t;
        bar_lds();  // B1: wlds holds W[i]

        // prefetch W[i+1] into registers (drains at stage point, after all
        // compute of i — loads cross B2 in flight, lgkmcnt-only barriers)
        float nv[16];
        if (t < GI - 1) {
            const float* wn = wp + (size_t)(t + 1) * (J_ * D_ * K_);
#pragma unroll
            for (int d = 0; d < 16; ++d) nv[d] = wn[d * K_];
        }

        // x B-frag for this i: x[b][i][8h..8h+7] packed bf16 (d ascending)
        union { uint4 u; short8 s; } bfrag;
        {
            const float* xp = xbase + (size_t)i * D_;
            const float4 x0 = reinterpret_cast<const float4*>(xp)[0];
            const float4 x1 = reinterpret_cast<const float4*>(xp)[1];
            bfrag.u.x = ((unsigned int)f2bf(x0.y) << 16) | f2bf(x0.x);
            bfrag.u.y = ((unsigned int)f2bf(x0.w) << 16) | f2bf(x0.z);
            bfrag.u.z = ((unsigned int)f2bf(x1.y) << 16) | f2bf(x1.x);
            bfrag.u.w = ((unsigned int)f2bf(x1.w) << 16) | f2bf(x1.z);
        }

        // ---- u_hat: 4 MFMAs, K=16 exact, all lanes productive ----
        float16v u[4];
#pragma unroll
        for (int m = 0; m < 4; ++m) {
            union { uint4 q; short8 s; } af;
            af.q = *reinterpret_cast<const uint4*>(wlds + abase + m * 768);
            float16v z;
#pragma unroll
            for (int r = 0; r < 16; ++r) z[r] = 0.f;
            u[m] = __builtin_amdgcn_mfma_f32_32x32x16_bf16(af.s, bfrag.s, z,
                                                           0, 0, 0);
        }

        if (MODE == 0) {
#pragma unroll
            for (int m = 0; m < 4; ++m) acc[m] += u[m];
            bar_lds();  // B2: all wlds reads of i complete
        } else {
            // softmax: dot over k (8 in-lane FMA + one xor32), exp, denom
            float e[4][2];
            float E = 0.f;
#pragma unroll
            for (int m = 0; m < 4; ++m)
#pragma unroll
                for (int jp = 0; jp < 2; ++jp) {
                    const int rb = jp * 8;
                    float p = u[m][rb + 0] * vv[m][jp][0].x +
                              u[m][rb + 1] * vv[m][jp][0].y +
                              u[m][rb + 2] * vv[m][jp][0].z +
                              u[m][rb + 3] * vv[m][jp][0].w +
                              u[m][rb + 4] * vv[m][jp][1].x +
                              u[m][rb + 5] * vv[m][jp][1].y +
                              u[m][rb + 6] * vv[m][jp][1].z +
                              u[m][rb + 7] * vv[m][jp][1].w;
                    p += __shfl_xor(p, 32, 64);  // other k-half (same b)
                    const float ee = __expf(p);  // |p| bounded; f32-safe
                    e[m][jp] = ee;
                    E += ee;
                }
            if (h == 0) ebuf[(((t & 1) * 2 + bt) * 4 + jg) * 32 + l31] = E;
            bar_lds();  // B2: ebuf visible; wlds reads complete
            float Et = 0.f;
#pragma unroll
            for (int g = 0; g < 4; ++g)
                Et += ebuf[(((t & 1) * 2 + bt) * 4 + g) * 32 + l31];
            const float r = __builtin_amdgcn_rcpf(Et);
#pragma unroll
            for (int m = 0; m < 4; ++m)
#pragma unroll
                for (int jp = 0; jp < 2; ++jp) {
                    const float c = e[m][jp] * r;
#pragma unroll
                    for (int q = 0; q < 8; ++q)
                        acc[m][jp * 8 + q] += c * u[m][jp * 8 + q];
                }
        }

        // ---- stage W[i+1] from prefetch regs (post-B2: WAR-safe) ----
        if (t < GI - 1) {
            unsigned int pk[8];
#pragma unroll
            for (int q = 0; q < 8; ++q)
                pk[q] = ((unsigned int)f2bf(nv[2 * q + 1]) << 16) |
                        f2bf(nv[2 * q]);
            uint4* dst = reinterpret_cast<uint4*>(wlds + (sj * 16 + sk) * 24);
            uint4 w0; w0.x = pk[0]; w0.y = pk[1]; w0.z = pk[2]; w0.w = pk[3];
            uint4 w1; w1.x = pk[4]; w1.y = pk[5]; w1.z = pk[6]; w1.w = pk[7];
            dst[0] = w0; dst[1] = w1;
        }
    }

    // ---- ctile transpose (aliases wlds/ebuf; bar fences last ebuf reads) --
    bar_lds();
    {
        float* cw = ct + w * (32 * 132);  // [b32][132] padded rows
#pragma unroll
        for (int m = 0; m < 4; ++m)
#pragma unroll
            for (int jp = 0; jp < 2; ++jp) {
                const int col = (m * 2 + jp) * 16 + 4 * h;
                float4 v0, v1;
                v0.x = acc[m][jp * 8 + 0]; v0.y = acc[m][jp * 8 + 1];
                v0.z = acc[m][jp * 8 + 2]; v0.w = acc[m][jp * 8 + 3];
                v1.x = acc[m][jp * 8 + 4]; v1.y = acc[m][jp * 8 + 5];
                v1.z = acc[m][jp * 8 + 6]; v1.w = acc[m][jp * 8 + 7];
                *reinterpret_cast<float4*>(cw + l31 * 132 + col) = v0;
                *reinterpret_cast<float4*>(cw + l31 * 132 + col + 8) = v1;
            }
    }
    bar_lds();
    // cooperative store: part[b][blk][jk] — 256-B contiguous per thread
    {
        const int bb = tid >> 3;
        const int oct = tid & 7;
        float* gp = part + ((size_t)bb * NBLK + blockIdx.x) * JK + oct * 64;
#pragma unroll
        for (int s = 0; s < 4; ++s) {
            const int j = oct * 4 + s;
            const float* src = ct + ((bb >> 5) + 2 * (j >> 3)) * (32 * 132) +
                               (bb & 31) * 132 + (j & 7) * 16;
#pragma unroll
            for (int q = 0; q < 4; ++q)
                reinterpret_cast<float4*>(gp + s * 16 + q * 4)[0] =
                    reinterpret_cast<const float4*>(src + q * 4)[0];
        }
    }
}

// ---------------------------------------------------------------------------
// Reduce NBLK partials + squash. part[b][p][jk]: block (bl,q4) walks p at
// 2-KB stride inside bl's contiguous 512-KB slab. Grid B_*4 x 512, 4-way
// h-split over p merged via LDS.
// MODE 0: vsum = squash(s/32). MODE 1: vsum += squash(s). MODE 2: out = ...
// ---------------------------------------------------------------------------
template <int MODE>
__global__ __launch_bounds__(512)
void caps_squashN(const float* __restrict__ part, float* __restrict__ vsum,
                  float* __restrict__ out) {
    __shared__ float red[3][128];
    const int bl = blockIdx.x >> 2;
    const int q4 = blockIdx.x & 3;
    const int jk128 = threadIdx.x & 127;
    const int h = threadIdx.x >> 7;  // 0..3
    const int jk = q4 * 128 + jk128;

    float s = 0.f;
#pragma unroll 8
    for (int p = h * (NBLK / 4); p < (h + 1) * (NBLK / 4); ++p)
        s += part[((size_t)bl * NBLK + p) * JK + jk];

    if (h > 0) red[h - 1][jk128] = s;
    __syncthreads();
    if (h == 0) {
        s += red[0][jk128] + red[1][jk128] + red[2][jk128];
        if (MODE == 0) s *= (1.f / 32.f);
        float qq = s * s;
        qq += __shfl_xor(qq, 1, 64);
        qq += __shfl_xor(qq, 2, 64);
        qq += __shfl_xor(qq, 4, 64);
        qq += __shfl_xor(qq, 8, 64);
        const float scale = qq / ((1.f + qq) * sqrtf(qq + 1e-7f));
        const float v = scale * s;
        if (MODE == 0)      vsum[bl * JK + jk] = v;
        else if (MODE == 1) vsum[bl * JK + jk] += v;
        else                out[(size_t)bl * JK + jk] = v;
    }
}

// ---------------------------------------------------------------------------
extern "C" void kernel_launch(void* const* d_in, const int* in_sizes, int n_in,
                              void* d_out, int out_size, void* d_ws,
                              size_t ws_size, hipStream_t stream) {
    const float* x = (const float*)d_in[0];  // [B,I,D] f32
    const float* W = (const float*)d_in[1];  // [I,J,D,K] f32
    float* out = (float*)d_out;              // [B,J,K] f32

    char* ws = (char*)d_ws;
    float* part = (float*)ws;  // [64][NBLK][512] f32 = 32 MB
    float* vsum =
        (float*)(ws + (size_t)B_ * I_ * JK * 2 + (size_t)64 * B_ * JK * 4);

    // round 0: uniform c = 1/32
    caps_pass<0><<<NBLK, 512, SMEM_BYTES, stream>>>(x, W, nullptr, part);
    caps_squashN<0><<<B_ * 4, 512, 0, stream>>>(part, vsum, nullptr);
    // round 1
    caps_pass<1><<<NBLK, 512, SMEM_BYTES, stream>>>(x, W, vsum, part);
    caps_squashN<1><<<B_ * 4, 512, 0, stream>>>(part, vsum, nullptr);
    // round 2
    caps_pass<1><<<NBLK, 512, SMEM_BYTES, stream>>>(x, W, vsum, part);
    caps_squashN<2><<<B_ * 4, 512, 0, stream>>>(part, vsum, out);
}